// Round 7
// baseline (235.881 us; speedup 1.0000x reference)
//
#include <hip/hip_runtime.h>

// HMM forward, log-semiring chunked scan, MFMA + single-kernel reduce.
// B=8, T=4096, S=64.  C=128 chunks of L=32 steps.
// Phase 1 (1024 WGs, 256 thr, 2 WGs/CU): chunk transfer matrix via bf16 MFMA.
//   R2-proven pipeline: one barrier/step, fB double-buffered, depth-1
//   global_load_lds prefetch issued at loop top, no vmcnt drain in-loop.
//   Emits Et (bf16, [chunk][j][i]) and row-log m (f32).
// Reduce (8 WGs, 512 thr): per batch, 8 waves fold 16 chunks each (identity
//   init), 2 waves fold 4 partials, 1 wave folds 2 + logsumexp matvec.
// R7 fix vs R5/R6: roundtrip scratch was pscr[16*PSS] but stores 64 rows
//   (4x overflow -> clobbered other waves' scratch and pm/sS -> NaN).
//   pscr deleted; pmat[v]/pmat[sb] (64 x PMS, wave-private in every phase
//   where used as scratch) serves as the roundtrip buffer.

#define HMM_B 8
#define HMM_T 4096
#define HMM_S 64
#define HMM_C 128
#define HMM_L (HMM_T / HMM_C)   // 32

typedef __attribute__((ext_vector_type(8))) short s16x8;
typedef __attribute__((ext_vector_type(4))) float f32x4;
typedef __attribute__((ext_vector_type(4))) unsigned int u32x4;

__device__ inline void gld16(const float* g, const float* l) {
  __builtin_amdgcn_global_load_lds((const __attribute__((address_space(1))) void*)g,
                                   (__attribute__((address_space(3))) void*)l, 16, 0, 0);
}

__device__ inline unsigned cvtpk(float lo, float hi) {
  unsigned r;
  asm("v_cvt_pk_bf16_f32 %0, %1, %2" : "=v"(r) : "v"(lo), "v"(hi));
  return r;
}

__device__ inline float dpp_fmax16(float x) {
  int xi = __float_as_int(x);
  x = fmaxf(x, __int_as_float(__builtin_amdgcn_mov_dpp(xi, 0xB1, 0xF, 0xF, 1)));
  xi = __float_as_int(x);
  x = fmaxf(x, __int_as_float(__builtin_amdgcn_mov_dpp(xi, 0x4E, 0xF, 0xF, 1)));
  xi = __float_as_int(x);
  x = fmaxf(x, __int_as_float(__builtin_amdgcn_mov_dpp(xi, 0x141, 0xF, 0xF, 1)));
  xi = __float_as_int(x);
  x = fmaxf(x, __int_as_float(__builtin_amdgcn_mov_dpp(xi, 0x140, 0xF, 0xF, 1)));
  return x;
}

__device__ inline float bflo(unsigned w) { return __uint_as_float(w << 16); }
__device__ inline float bfhi(unsigned w) { return __uint_as_float(w & 0xffff0000u); }

// ---------------- Phase 1 ----------------

__global__ __launch_bounds__(256, 2)
void hmm_phase1(const float* __restrict__ lf, unsigned short* __restrict__ wsEt,
                float* __restrict__ wsM) {
  // LDS: 60416 B -> 2 WGs/CU.
  __shared__ struct {
    float fbuf[2][4096];            // f tile; rows are wave-private
    unsigned short fB[2][4096];     // F bf16, B-frag-linear slots (dbuf)
    unsigned short escr[4][1408];   // per-wave E rows, stride 88 ushorts
  } sm;

  const int tid = threadIdx.x;
  const int w   = tid >> 6;     // wave id 0..3 -> output rows 16w..16w+15
  const int l   = tid & 63;     // lane
  const int wg  = blockIdx.x;
  const int bb  = wg >> 7;
  const int cc  = wg & (HMM_C - 1);
  const float* fbase = lf + ((size_t)(bb * HMM_T + cc * HMM_L)) * (HMM_S * HMM_S);

  auto issue = [&](int t) {
    const int par = t & 1;
    const float* fb = fbase + (size_t)t * 4096;
#pragma unroll
    for (int u = 0; u < 4; ++u) {
      int slot = (w * 4 + u) * 64 + l;        // 16B slot index
      int k    = slot >> 4;                   // row of f
      int q16  = slot & 15;                   // swizzled slot-in-row
      const float* src = fb + k * 64 + ((q16 ^ (k & 7)) << 2);
      gld16(src, &sm.fbuf[par][(w * 4 + u) * 256]);
    }
  };

  issue(0);

  float mracc0 = 0.f, mracc1 = 0.f, mracc2 = 0.f, mracc3 = 0.f;
  const int c4 = l & 15, q = l >> 4;

  for (int t = 0; t < HMM_L; ++t) {
    const int par = t & 1;
    if (t + 1 < HMM_L) issue(t + 1);

    if (t < HMM_L - 1) asm volatile("s_waitcnt vmcnt(4)" ::: "memory");
    else               asm volatile("s_waitcnt vmcnt(0)" ::: "memory");
    __builtin_amdgcn_sched_barrier(0);

    // ---- exp + transpose + pack: my wave's 16 rows -> fB (B-frag-linear)
#pragma unroll
    for (int u = 0; u < 2; ++u) {
      const int g = 2 * w + (l >> 5);         // k-octet index (within my band)
      const int j = (l & 31) + 32 * u;        // column of f
      float v[8];
#pragma unroll
      for (int e = 0; e < 8; ++e) {
        int k = 8 * g + e;
        v[e] = sm.fbuf[par][k * 64 + (((j >> 2) ^ (k & 7)) << 2) + (j & 3)];
      }
      unsigned p0 = cvtpk(__expf(v[0]), __expf(v[1]));
      unsigned p1 = cvtpk(__expf(v[2]), __expf(v[3]));
      unsigned p2 = cvtpk(__expf(v[4]), __expf(v[5]));
      unsigned p3 = cvtpk(__expf(v[6]), __expf(v[7]));
      int slot = ((g >> 2) * 4 + (j >> 4)) * 64 + ((g & 3) << 4) + (j & 15);
      u32x4 o; o.x = p0; o.y = p1; o.z = p2; o.w = p3;
      *(u32x4*)&sm.fB[par][slot * 8] = o;
    }

    asm volatile("s_waitcnt lgkmcnt(0)" ::: "memory");
    __builtin_amdgcn_sched_barrier(0);
    __builtin_amdgcn_s_barrier();     // the ONLY barrier per step

    // ---- A fragments (my E rows; identity at t=0)
    s16x8 a0, a1;
    if (t == 0) {
      const int iloc = 16 * w + (l & 15);
      const int kb0 = (l >> 4) * 8, kb1 = 32 + (l >> 4) * 8;
#pragma unroll
      for (int e = 0; e < 8; ++e) {
        a0[e] = (short)((kb0 + e == iloc) ? 0x3F80 : 0);
        a1[e] = (short)((kb1 + e == iloc) ? 0x3F80 : 0);
      }
    } else {
      a0 = *(const s16x8*)&sm.escr[w][(l & 15) * 88 + ((l >> 4) * 8)];
      a1 = *(const s16x8*)&sm.escr[w][(l & 15) * 88 + 32 + ((l >> 4) * 8)];
    }

    // ---- P = E*F : 4 col-tiles x (K=64 as 2 mfma)
    f32x4 acc[4];
#pragma unroll
    for (int n = 0; n < 4; ++n) {
      s16x8 b0 = *(const s16x8*)&sm.fB[par][((0 + n) * 64 + l) * 8];
      s16x8 b1 = *(const s16x8*)&sm.fB[par][((4 + n) * 64 + l) * 8];
      f32x4 c = {0.f, 0.f, 0.f, 0.f};
      c = __builtin_amdgcn_mfma_f32_16x16x32_bf16(a0, b0, c, 0, 0, 0);
      c = __builtin_amdgcn_mfma_f32_16x16x32_bf16(a1, b1, c, 0, 0, 0);
      acc[n] = c;
    }

    // ---- epilogue: rowmax, rescale, log-accumulate, store E'
    float inv[4];
    {
      float m0 = fmaxf(fmaxf(acc[0][0], acc[1][0]), fmaxf(acc[2][0], acc[3][0]));
      float m1 = fmaxf(fmaxf(acc[0][1], acc[1][1]), fmaxf(acc[2][1], acc[3][1]));
      float m2 = fmaxf(fmaxf(acc[0][2], acc[1][2]), fmaxf(acc[2][2], acc[3][2]));
      float m3 = fmaxf(fmaxf(acc[0][3], acc[1][3]), fmaxf(acc[2][3], acc[3][3]));
      m0 = dpp_fmax16(m0); m1 = dpp_fmax16(m1);
      m2 = dpp_fmax16(m2); m3 = dpp_fmax16(m3);
      mracc0 += __log2f(m0); mracc1 += __log2f(m1);
      mracc2 += __log2f(m2); mracc3 += __log2f(m3);
      inv[0] = __builtin_amdgcn_rcpf(m0); inv[1] = __builtin_amdgcn_rcpf(m1);
      inv[2] = __builtin_amdgcn_rcpf(m2); inv[3] = __builtin_amdgcn_rcpf(m3);
    }
#pragma unroll
    for (int n = 0; n < 4; ++n) {
      unsigned p0 = cvtpk(acc[n][0] * inv[0], acc[n][1] * inv[1]);
      unsigned p1 = cvtpk(acc[n][2] * inv[2], acc[n][3] * inv[3]);
      sm.escr[w][(4 * q + 0) * 88 + 16 * n + c4] = (unsigned short)(p0 & 0xffffu);
      sm.escr[w][(4 * q + 1) * 88 + 16 * n + c4] = (unsigned short)(p0 >> 16);
      sm.escr[w][(4 * q + 2) * 88 + 16 * n + c4] = (unsigned short)(p1 & 0xffffu);
      sm.escr[w][(4 * q + 3) * 88 + 16 * n + c4] = (unsigned short)(p1 >> 16);
    }
  }

  // ---- write chunk results (escr is wave-private; no barrier needed)
  {
    const size_t cb = ((size_t)(bb * HMM_C + cc)) * 4096;  // ushort elems
    const int j = tid & 63, p4 = tid >> 6;
    unsigned short o0[8], o1[8];
#pragma unroll
    for (int rl = 0; rl < 8; ++rl)  o0[rl] = sm.escr[p4][rl * 88 + j];
#pragma unroll
    for (int rl = 0; rl < 8; ++rl)  o1[rl] = sm.escr[p4][(rl + 8) * 88 + j];
    *(u32x4*)&wsEt[cb + j * 64 + p4 * 16]     = *(u32x4*)o0;
    *(u32x4*)&wsEt[cb + j * 64 + p4 * 16 + 8] = *(u32x4*)o1;

    if (c4 == 0) {
      const float ln2 = 0.6931471805599453f;
      float* dst = wsM + (size_t)(bb * HMM_C + cc) * 64 + 16 * w + 4 * q;
      dst[0] = mracc0 * ln2; dst[1] = mracc1 * ln2;
      dst[2] = mracc2 * ln2; dst[3] = mracc3 * ln2;
    }
  }
}

// ---------------- Reduce (one kernel: 3 fold levels + final) ----------------
// Fold: prod' = prod . diag(exp(m_c - nu)) . E_c, row-normalized;
//       pmAcc[i] += nu + log(rowmax_i).
// Scratch discipline: pmat[s] (64 x PMS) doubles as the wave's roundtrip
// scratch in the phase where that wave owns slot s; storeEt overwrites it
// with the Et-format partial only at the wave's LAST fold of the phase.

#define PMS 72   // pmat row stride (ushorts); 72*2B = 144 B, 16B-aligned rows

__global__ __launch_bounds__(512)
void hmm_reduce(const unsigned short* __restrict__ Et, const float* __restrict__ M,
                const float* __restrict__ linit, float* __restrict__ out) {
  __shared__ unsigned short pmat[8][PMS * 64];  // partials + roundtrip scratch
  __shared__ float pm[8][64];
  __shared__ float sS[8][64];
  __shared__ float sLin[64];
  __shared__ float sW[64];

  const int tid = threadIdx.x;
  const int v = tid >> 6, l = tid & 63, c4 = l & 15, q = l >> 4;
  const int b = blockIdx.x;

  if (tid < 64) sLin[tid] = linit[b * 64 + tid];
  pm[v][l] = 0.0f;

  // identity A fragments: afr[m][h][e] = (32h+8q+e == 16m+c4)
  s16x8 afr[4][2];
#pragma unroll
  for (int m = 0; m < 4; ++m)
#pragma unroll
    for (int h = 0; h < 2; ++h)
#pragma unroll
      for (int e = 0; e < 8; ++e)
        afr[m][h][e] = (short)((32 * h + 8 * q + e == 16 * m + c4) ? 0x3F80 : 0);

  f32x4 acc[4][4];
  float rmax[4][4];

  auto fold = [&](u32x4 (&bcur)[2][4], float mcur, float* pmAcc, float* sSv) {
    float nu = mcur;
    nu = fmaxf(nu, __shfl_xor(nu, 1));  nu = fmaxf(nu, __shfl_xor(nu, 2));
    nu = fmaxf(nu, __shfl_xor(nu, 4));  nu = fmaxf(nu, __shfl_xor(nu, 8));
    nu = fmaxf(nu, __shfl_xor(nu, 16)); nu = fmaxf(nu, __shfl_xor(nu, 32));
    sSv[l] = __expf(mcur - nu);
    s16x8 bfr[2][4];
#pragma unroll
    for (int h = 0; h < 2; ++h) {
      f32x4 s0 = *(const f32x4*)&sSv[h * 32 + q * 8];
      f32x4 s1 = *(const f32x4*)&sSv[h * 32 + q * 8 + 4];
#pragma unroll
      for (int n = 0; n < 4; ++n) {
        u32x4 raw = bcur[h][n];
        unsigned p0 = cvtpk(bflo(raw.x) * s0[0], bfhi(raw.x) * s0[1]);
        unsigned p1 = cvtpk(bflo(raw.y) * s0[2], bfhi(raw.y) * s0[3]);
        unsigned p2 = cvtpk(bflo(raw.z) * s1[0], bfhi(raw.z) * s1[1]);
        unsigned p3 = cvtpk(bflo(raw.w) * s1[2], bfhi(raw.w) * s1[3]);
        u32x4 o; o.x = p0; o.y = p1; o.z = p2; o.w = p3;
        bfr[h][n] = *(s16x8*)&o;
      }
    }
#pragma unroll
    for (int m = 0; m < 4; ++m)
#pragma unroll
      for (int n = 0; n < 4; ++n) {
        f32x4 c = {0.f, 0.f, 0.f, 0.f};
        c = __builtin_amdgcn_mfma_f32_16x16x32_bf16(afr[m][0], bfr[0][n], c, 0, 0, 0);
        c = __builtin_amdgcn_mfma_f32_16x16x32_bf16(afr[m][1], bfr[1][n], c, 0, 0, 0);
        acc[m][n] = c;
      }
#pragma unroll
    for (int m = 0; m < 4; ++m)
#pragma unroll
      for (int r = 0; r < 4; ++r) {
        float x = fmaxf(fmaxf(acc[m][0][r], acc[m][1][r]),
                        fmaxf(acc[m][2][r], acc[m][3][r]));
        x = fmaxf(x, __shfl_xor(x, 1));
        x = fmaxf(x, __shfl_xor(x, 2));
        x = fmaxf(x, __shfl_xor(x, 4));
        x = fmaxf(x, __shfl_xor(x, 8));
        rmax[m][r] = fmaxf(x, 1e-30f);   // guard: log(0)/rcp(0)
      }
    if (c4 == 0) {
#pragma unroll
      for (int m = 0; m < 4; ++m)
#pragma unroll
        for (int r = 0; r < 4; ++r)
          pmAcc[16 * m + 4 * q + r] += nu + __logf(rmax[m][r]);
    }
  };

  auto roundtrip = [&](unsigned short* ps) {  // acc -> row-major ps -> afr
#pragma unroll
    for (int m = 0; m < 4; ++m) {
      float i0 = __builtin_amdgcn_rcpf(rmax[m][0]);
      float i1 = __builtin_amdgcn_rcpf(rmax[m][1]);
      float i2 = __builtin_amdgcn_rcpf(rmax[m][2]);
      float i3 = __builtin_amdgcn_rcpf(rmax[m][3]);
#pragma unroll
      for (int n = 0; n < 4; ++n) {
        unsigned p01 = cvtpk(acc[m][n][0] * i0, acc[m][n][1] * i1);
        unsigned p23 = cvtpk(acc[m][n][2] * i2, acc[m][n][3] * i3);
        ps[(16 * m + 4 * q + 0) * PMS + 16 * n + c4] = (unsigned short)(p01 & 0xffffu);
        ps[(16 * m + 4 * q + 1) * PMS + 16 * n + c4] = (unsigned short)(p01 >> 16);
        ps[(16 * m + 4 * q + 2) * PMS + 16 * n + c4] = (unsigned short)(p23 & 0xffffu);
        ps[(16 * m + 4 * q + 3) * PMS + 16 * n + c4] = (unsigned short)(p23 >> 16);
      }
    }
#pragma unroll
    for (int m = 0; m < 4; ++m)
#pragma unroll
      for (int h = 0; h < 2; ++h)
        afr[m][h] = *(const s16x8*)&ps[(16 * m + c4) * PMS + 32 * h + 8 * q];
  };

  auto storeEt = [&](unsigned short* pd) {    // acc -> Et-layout pd
#pragma unroll
    for (int m = 0; m < 4; ++m) {
      float i0 = __builtin_amdgcn_rcpf(rmax[m][0]);
      float i1 = __builtin_amdgcn_rcpf(rmax[m][1]);
      float i2 = __builtin_amdgcn_rcpf(rmax[m][2]);
      float i3 = __builtin_amdgcn_rcpf(rmax[m][3]);
#pragma unroll
      for (int n = 0; n < 4; ++n) {
        unsigned p01 = cvtpk(acc[m][n][0] * i0, acc[m][n][1] * i1);
        unsigned p23 = cvtpk(acc[m][n][2] * i2, acc[m][n][3] * i3);
        unsigned long long packed = (unsigned long long)p01 |
                                    ((unsigned long long)p23 << 32);
        *(unsigned long long*)&pd[(16 * n + c4) * PMS + 16 * m + 4 * q] = packed;
      }
    }
  };

  // ---- level 0: wave v folds chunks [b*128 + 16v, +16), identity init
  {
    const int cidx0 = b * HMM_C + 16 * v;
    u32x4 braw[2][4];
    float mv;
#pragma unroll
    for (int h = 0; h < 2; ++h)
#pragma unroll
      for (int n = 0; n < 4; ++n)
        braw[h][n] = *(const u32x4*)&Et[(size_t)cidx0 * 4096 +
                                        (16 * n + c4) * 64 + 32 * h + 8 * q];
    mv = M[(size_t)cidx0 * 64 + l];

    for (int c = 0; c < 16; ++c) {
      u32x4 bcur[2][4];
#pragma unroll
      for (int h = 0; h < 2; ++h)
#pragma unroll
        for (int n = 0; n < 4; ++n) bcur[h][n] = braw[h][n];
      float mcur = mv;
      if (c < 15) {
        const size_t cb = (size_t)(cidx0 + c + 1) * 4096;
#pragma unroll
        for (int h = 0; h < 2; ++h)
#pragma unroll
          for (int n = 0; n < 4; ++n)
            braw[h][n] = *(const u32x4*)&Et[cb + (16 * n + c4) * 64 + 32 * h + 8 * q];
        mv = M[(size_t)(cidx0 + c + 1) * 64 + l];
      }
      fold(bcur, mcur, pm[v], sS[v]);
      if (c < 15) roundtrip(pmat[v]);   // wave-private scratch
      else        storeEt(pmat[v]);     // final: Et-format partial
    }
  }
  __syncthreads();

  // ---- level 1: waves 0,1 fold partial slots [4v, 4v+4)
  if (v < 2) {
    const int sb = 4 * v;
#pragma unroll
    for (int m = 0; m < 4; ++m)
#pragma unroll
      for (int h = 0; h < 2; ++h)
#pragma unroll
        for (int e = 0; e < 8; ++e)
          afr[m][h][e] = (short)pmat[sb][(32 * h + 8 * q + e) * PMS + 16 * m + c4];
    for (int c = 1; c < 4; ++c) {
      u32x4 bcur[2][4];
#pragma unroll
      for (int h = 0; h < 2; ++h)
#pragma unroll
        for (int n = 0; n < 4; ++n)
          bcur[h][n] = *(const u32x4*)&pmat[sb + c][(16 * n + c4) * PMS + 32 * h + 8 * q];
      float mcur = pm[sb + c][l];
      fold(bcur, mcur, pm[sb], sS[v]);
      // pmat[sb]'s A-content was consumed into afr before the loop; safe as
      // scratch now.  v==1 finishes by overwriting pmat[4] in Et format.
      if (v == 0)      roundtrip(pmat[0]);
      else if (c < 3)  roundtrip(pmat[4]);
      else             storeEt(pmat[4]);
    }
  }
  __syncthreads();

  // ---- level 2 + final: wave 0 folds pmat[4], then logsumexp matvec
  if (v == 0) {
    u32x4 bcur[2][4];
#pragma unroll
    for (int h = 0; h < 2; ++h)
#pragma unroll
      for (int n = 0; n < 4; ++n)
        bcur[h][n] = *(const u32x4*)&pmat[4][(16 * n + c4) * PMS + 32 * h + 8 * q];
    float mcur = pm[4][l];

    float nu = mcur;
    nu = fmaxf(nu, __shfl_xor(nu, 1));  nu = fmaxf(nu, __shfl_xor(nu, 2));
    nu = fmaxf(nu, __shfl_xor(nu, 4));  nu = fmaxf(nu, __shfl_xor(nu, 8));
    nu = fmaxf(nu, __shfl_xor(nu, 16)); nu = fmaxf(nu, __shfl_xor(nu, 32));
    sS[0][l] = __expf(mcur - nu);
    s16x8 bfr[2][4];
#pragma unroll
    for (int h = 0; h < 2; ++h) {
      f32x4 s0 = *(const f32x4*)&sS[0][h * 32 + q * 8];
      f32x4 s1 = *(const f32x4*)&sS[0][h * 32 + q * 8 + 4];
#pragma unroll
      for (int n = 0; n < 4; ++n) {
        u32x4 raw = bcur[h][n];
        unsigned p0 = cvtpk(bflo(raw.x) * s0[0], bfhi(raw.x) * s0[1]);
        unsigned p1 = cvtpk(bflo(raw.y) * s0[2], bfhi(raw.y) * s0[3]);
        unsigned p2 = cvtpk(bflo(raw.z) * s1[0], bfhi(raw.z) * s1[1]);
        unsigned p3 = cvtpk(bflo(raw.w) * s1[2], bfhi(raw.w) * s1[3]);
        u32x4 o; o.x = p0; o.y = p1; o.z = p2; o.w = p3;
        bfr[h][n] = *(s16x8*)&o;
      }
    }
#pragma unroll
    for (int m = 0; m < 4; ++m)
#pragma unroll
      for (int n = 0; n < 4; ++n) {
        f32x4 c = {0.f, 0.f, 0.f, 0.f};
        c = __builtin_amdgcn_mfma_f32_16x16x32_bf16(afr[m][0], bfr[0][n], c, 0, 0, 0);
        c = __builtin_amdgcn_mfma_f32_16x16x32_bf16(afr[m][1], bfr[1][n], c, 0, 0, 0);
        acc[m][n] = c;
      }

    // out[b] = (mx + nu) + log( sum_i w_i * rowsum_i(acc) )
    float tv = sLin[l] + pm[0][l];
    float mx = tv;
    mx = fmaxf(mx, __shfl_xor(mx, 1));  mx = fmaxf(mx, __shfl_xor(mx, 2));
    mx = fmaxf(mx, __shfl_xor(mx, 4));  mx = fmaxf(mx, __shfl_xor(mx, 8));
    mx = fmaxf(mx, __shfl_xor(mx, 16)); mx = fmaxf(mx, __shfl_xor(mx, 32));
    sW[l] = __expf(tv - mx);

    float tot = 0.f;
#pragma unroll
    for (int m = 0; m < 4; ++m)
#pragma unroll
      for (int r = 0; r < 4; ++r) {
        float rs = acc[m][0][r] + acc[m][1][r] + acc[m][2][r] + acc[m][3][r];
        rs += __shfl_xor(rs, 1); rs += __shfl_xor(rs, 2);
        rs += __shfl_xor(rs, 4); rs += __shfl_xor(rs, 8);
        if (c4 == 0) tot += sW[16 * m + 4 * q + r] * rs;
      }
    tot += __shfl_xor(tot, 16);
    tot += __shfl_xor(tot, 32);
    if (l == 0) out[b] = mx + nu + __logf(tot);
  }
}

extern "C" void kernel_launch(void* const* d_in, const int* in_sizes, int n_in,
                              void* d_out, int out_size, void* d_ws, size_t ws_size,
                              hipStream_t stream) {
  (void)in_sizes; (void)n_in; (void)out_size; (void)ws_size;
  const float* lf    = (const float*)d_in[0];  // [B,T,S,S] fp32
  const float* linit = (const float*)d_in[1];  // [B,S] fp32
  float* out = (float*)d_out;                  // [B] fp32

  unsigned short* Et_A = (unsigned short*)d_ws;                 // 8 MB bf16
  float*          M_A  = (float*)(Et_A + (size_t)1024 * 4096);  // 256 KB f32

  hmm_phase1<<<dim3(HMM_B * HMM_C), dim3(256), 0, stream>>>(lf, Et_A, M_A);
  hmm_reduce<<<dim3(HMM_B), dim3(512), 0, stream>>>(Et_A, M_A, linit, out);
}

// Round 8
// 185.220 us; speedup vs baseline: 1.2735x; 1.2735x over previous
//
#include <hip/hip_runtime.h>

// HMM forward, log-semiring chunked scan. R8: reverse-product phase1.
// B=8, T=4096, S=64.  C=128 chunks of L=32 steps.
// Phase 1 (1024 WGs, 256 thr, 4 WGs/CU): G = F_t * G_old, t = 31..0.
//   F rows are the MFMA A-operand (contiguous!): staged global->REGISTERS
//   (4 dwordx4/lane, depth-2, compiler vmcnt). State G in 8KB B-frag-linear
//   LDS (byte-layout identical to R2's verified fB), double-buffered.
//   COLUMN-normalized every 4th step (cross-wave colmax via LDS).
//   Output: wsX[chunk] = row-major G (bf16) = B-operand layout of G^T;
//           wsM[chunk] = col-logs (f32).
// Reduce (8 WGs, 512 thr): computes M^T = C127^T * ... * C0^T using R7's
//   verified fold algebra on transposed chunks in REVERSE chunk order.
//   Final: out = nu + mL + kap + log( sum_j e^{pm_j-kap} * <row_j, e^{linit-mL}> ).

#define HMM_B 8
#define HMM_T 4096
#define HMM_S 64
#define HMM_C 128
#define HMM_L 32

typedef __attribute__((ext_vector_type(8))) short s16x8;
typedef __attribute__((ext_vector_type(4))) float f32x4;
typedef __attribute__((ext_vector_type(4))) unsigned int u32x4;
typedef unsigned long long u64t;

__device__ inline unsigned cvtpk(float lo, float hi) {
  unsigned r;
  asm("v_cvt_pk_bf16_f32 %0, %1, %2" : "=v"(r) : "v"(lo), "v"(hi));
  return r;
}
__device__ inline float bflo(unsigned w) { return __uint_as_float(w << 16); }
__device__ inline float bfhi(unsigned w) { return __uint_as_float(w & 0xffff0000u); }

// ---------------- Phase 1 ----------------

__global__ __launch_bounds__(256, 4)
void hmm_phase1(const float* __restrict__ lf, unsigned short* __restrict__ wsX,
                float* __restrict__ wsM) {
  // LDS: 16384 (gscr) + 1024 (cmax) + 9216 (orow) = 26624 B -> 4+ WGs/CU.
  __shared__ struct {
    unsigned short gscr[2][4096];   // G in B-frag-linear slots, dbuf
    float cmax[256];                // [j][w] per-wave colmax partials
    unsigned short orow[64 * 72];   // final G row-major, stride 72
  } sm;

  const int tid = threadIdx.x;
  const int w = tid >> 6, l = tid & 63;
  const int c4 = l & 15, q = l >> 4;
  const int wg = blockIdx.x;
  const int bb = wg >> 7, cc = wg & (HMM_C - 1);
  const size_t chunkbase = ((size_t)(bb * HMM_T + cc * HMM_L)) * 4096;
  // my A-operand source: rows 16w+c4, k-start 8q (+0/4, +32/36)
  const float* fb0 = lf + chunkbase + (size_t)(16 * w + c4) * 64 + 8 * q;

  // ---- init gscr[0] = Identity (B-frag-linear: slot(g,j), g=row-octet)
#pragma unroll
  for (int s = 0; s < 2; ++s) {
    int gg = w * 2 + s;   // 0..7
    int j = l;
    int slot = ((gg >> 2) * 4 + (j >> 4)) * 64 + (gg & 3) * 16 + (j & 15);
    unsigned short e8[8];
#pragma unroll
    for (int e = 0; e < 8; ++e)
      e8[e] = (unsigned short)((8 * gg + e == j) ? 0x3F80 : 0);
    *(u32x4*)&sm.gscr[0][slot * 8] = *(const u32x4*)e8;
  }
  float macc[4] = {0.f, 0.f, 0.f, 0.f};
  __syncthreads();

  f32x4 acc[4];

  auto ldf = [&](int t, float4& d0, float4& d1, float4& d2, float4& d3) {
    const float* p = fb0 + (size_t)t * 4096;
    d0 = *(const float4*)(p);
    d1 = *(const float4*)(p + 4);
    d2 = *(const float4*)(p + 32);
    d3 = *(const float4*)(p + 36);
  };

  auto step = [&](float4 f0, float4 f1, float4 f2, float4 f3, int pr, int t) {
    // A = exp(f rows), k ascending
    u32x4 ua, ub;
    ua.x = cvtpk(__expf(f0.x), __expf(f0.y));
    ua.y = cvtpk(__expf(f0.z), __expf(f0.w));
    ua.z = cvtpk(__expf(f1.x), __expf(f1.y));
    ua.w = cvtpk(__expf(f1.z), __expf(f1.w));
    ub.x = cvtpk(__expf(f2.x), __expf(f2.y));
    ub.y = cvtpk(__expf(f2.z), __expf(f2.w));
    ub.z = cvtpk(__expf(f3.x), __expf(f3.y));
    ub.w = cvtpk(__expf(f3.z), __expf(f3.w));
    s16x8 a0 = *(s16x8*)&ua, a1 = *(s16x8*)&ub;
#pragma unroll
    for (int n = 0; n < 4; ++n) {
      s16x8 b0 = *(const s16x8*)&sm.gscr[pr][(n * 64 + l) * 8];
      s16x8 b1 = *(const s16x8*)&sm.gscr[pr][((4 + n) * 64 + l) * 8];
      f32x4 c = {0.f, 0.f, 0.f, 0.f};
      c = __builtin_amdgcn_mfma_f32_16x16x32_bf16(a0, b0, c, 0, 0, 0);
      c = __builtin_amdgcn_mfma_f32_16x16x32_bf16(a1, b1, c, 0, 0, 0);
      acc[n] = c;
    }
    const bool rs = (t & 3) == 0;   // rescale every 4th step (incl. t=0)
    float inv[4] = {1.f, 1.f, 1.f, 1.f};
    if (rs) {
#pragma unroll
      for (int n = 0; n < 4; ++n) {
        float pmx = fmaxf(fmaxf(acc[n][0], acc[n][1]), fmaxf(acc[n][2], acc[n][3]));
        pmx = fmaxf(pmx, __shfl_xor(pmx, 16));
        pmx = fmaxf(pmx, __shfl_xor(pmx, 32));
        if (l < 16) sm.cmax[(16 * n + l) * 4 + w] = pmx;
      }
      __syncthreads();
#pragma unroll
      for (int n = 0; n < 4; ++n) {
        f32x4 cm = *(const f32x4*)&sm.cmax[(16 * n + c4) * 4];
        float m = fmaxf(fmaxf(cm[0], cm[1]), fmaxf(cm[2], cm[3]));
        m = fmaxf(m, 1e-30f);
        macc[n] += __log2f(m);
        inv[n] = __builtin_amdgcn_rcpf(m);
      }
    }
    if (t == 0) {
      // final: normalized acc -> orow (row-major), skip gscr store
#pragma unroll
      for (int n = 0; n < 4; ++n) {
        unsigned p01 = cvtpk(acc[n][0] * inv[n], acc[n][1] * inv[n]);
        unsigned p23 = cvtpk(acc[n][2] * inv[n], acc[n][3] * inv[n]);
        int base = 16 * n + c4, i0 = 16 * w + 4 * q;
        sm.orow[(i0 + 0) * 72 + base] = (unsigned short)(p01 & 0xffffu);
        sm.orow[(i0 + 1) * 72 + base] = (unsigned short)(p01 >> 16);
        sm.orow[(i0 + 2) * 72 + base] = (unsigned short)(p23 & 0xffffu);
        sm.orow[(i0 + 3) * 72 + base] = (unsigned short)(p23 >> 16);
      }
    } else {
      const int gg = 2 * w + (q >> 1);   // row-octet of rows 16w+4q..+3
#pragma unroll
      for (int n = 0; n < 4; ++n) {
        float s0, s1, s2, s3;
        if (rs) {
          s0 = acc[n][0] * inv[n]; s1 = acc[n][1] * inv[n];
          s2 = acc[n][2] * inv[n]; s3 = acc[n][3] * inv[n];
        } else {
          s0 = acc[n][0]; s1 = acc[n][1]; s2 = acc[n][2]; s3 = acc[n][3];
        }
        unsigned lo = cvtpk(s0, s1), hi = cvtpk(s2, s3);
        int slot = ((gg >> 2) * 4 + n) * 64 + (gg & 3) * 16 + c4;
        *(u64t*)((char*)sm.gscr[pr ^ 1] + slot * 16 + (q & 1) * 8) =
            (u64t)lo | ((u64t)hi << 32);
      }
    }
    __syncthreads();
  };

  float4 fA0, fA1, fA2, fA3, fB0, fB1, fB2, fB3;
  ldf(31, fA0, fA1, fA2, fA3);
  for (int tt = 0; tt < 32; tt += 2) {
    const int t0 = 31 - tt;
    ldf(t0 - 1, fB0, fB1, fB2, fB3);          // t0 >= 1 always here
    step(fA0, fA1, fA2, fA3, tt & 1, t0);
    if (t0 - 2 >= 0) ldf(t0 - 2, fA0, fA1, fA2, fA3);
    step(fB0, fB1, fB2, fB3, (tt + 1) & 1, t0 - 1);
  }

  // ---- write chunk results: wsX = row-major G (coalesced), wsM = col-logs
  {
    const size_t cb = ((size_t)(bb * HMM_C + cc)) * 4096;
    const int i = tid >> 2, c16 = (tid & 3) * 16;
    u32x4 v0 = *(const u32x4*)&sm.orow[i * 72 + c16];
    u32x4 v1 = *(const u32x4*)&sm.orow[i * 72 + c16 + 8];
    *(u32x4*)&wsX[cb + i * 64 + c16] = v0;
    *(u32x4*)&wsX[cb + i * 64 + c16 + 8] = v1;

    if (w == 0 && l < 16) {
      const float ln2 = 0.6931471805599453f;
#pragma unroll
      for (int n = 0; n < 4; ++n)
        wsM[(size_t)(bb * HMM_C + cc) * 64 + 16 * n + l] = macc[n] * ln2;
    }
  }
}

// ---------------- Reduce (R7's verified folds, transposed-chunk order) -----
// Folds T_s = C_{127-s}^T left-to-right; T's B-frag = wsX row-major data.
// Fold: prod' = prod . diag(exp(m_c - nu)) . T_c, row-normalized;
//       pmAcc[i] += nu + log(rowmax_i).

#define PMS 72   // pmat row stride (ushorts); 144 B, 16B-aligned rows

__global__ __launch_bounds__(512)
void hmm_reduce(const unsigned short* __restrict__ Xt, const float* __restrict__ M,
                const float* __restrict__ linit, float* __restrict__ out) {
  __shared__ unsigned short pmat[8][PMS * 64];  // partials + roundtrip scratch
  __shared__ float pm[8][64];
  __shared__ float sS[8][64];
  __shared__ float sLin[64];

  const int tid = threadIdx.x;
  const int v = tid >> 6, l = tid & 63, c4 = l & 15, q = l >> 4;
  const int b = blockIdx.x;

  if (tid < 64) sLin[tid] = linit[b * 64 + tid];
  pm[v][l] = 0.0f;

  // identity A fragments
  s16x8 afr[4][2];
#pragma unroll
  for (int m = 0; m < 4; ++m)
#pragma unroll
    for (int h = 0; h < 2; ++h)
#pragma unroll
      for (int e = 0; e < 8; ++e)
        afr[m][h][e] = (short)((32 * h + 8 * q + e == 16 * m + c4) ? 0x3F80 : 0);

  f32x4 acc[4][4];
  float rmax[4][4];

  auto fold = [&](u32x4 (&bcur)[2][4], float mcur, float* pmAcc, float* sSv) {
    float nu = mcur;
    nu = fmaxf(nu, __shfl_xor(nu, 1));  nu = fmaxf(nu, __shfl_xor(nu, 2));
    nu = fmaxf(nu, __shfl_xor(nu, 4));  nu = fmaxf(nu, __shfl_xor(nu, 8));
    nu = fmaxf(nu, __shfl_xor(nu, 16)); nu = fmaxf(nu, __shfl_xor(nu, 32));
    sSv[l] = __expf(mcur - nu);
    s16x8 bfr[2][4];
#pragma unroll
    for (int h = 0; h < 2; ++h) {
      f32x4 s0 = *(const f32x4*)&sSv[h * 32 + q * 8];
      f32x4 s1 = *(const f32x4*)&sSv[h * 32 + q * 8 + 4];
#pragma unroll
      for (int n = 0; n < 4; ++n) {
        u32x4 raw = bcur[h][n];
        unsigned p0 = cvtpk(bflo(raw.x) * s0[0], bfhi(raw.x) * s0[1]);
        unsigned p1 = cvtpk(bflo(raw.y) * s0[2], bfhi(raw.y) * s0[3]);
        unsigned p2 = cvtpk(bflo(raw.z) * s1[0], bfhi(raw.z) * s1[1]);
        unsigned p3 = cvtpk(bflo(raw.w) * s1[2], bfhi(raw.w) * s1[3]);
        u32x4 o; o.x = p0; o.y = p1; o.z = p2; o.w = p3;
        bfr[h][n] = *(s16x8*)&o;
      }
    }
#pragma unroll
    for (int m = 0; m < 4; ++m)
#pragma unroll
      for (int n = 0; n < 4; ++n) {
        f32x4 c = {0.f, 0.f, 0.f, 0.f};
        c = __builtin_amdgcn_mfma_f32_16x16x32_bf16(afr[m][0], bfr[0][n], c, 0, 0, 0);
        c = __builtin_amdgcn_mfma_f32_16x16x32_bf16(afr[m][1], bfr[1][n], c, 0, 0, 0);
        acc[m][n] = c;
      }
#pragma unroll
    for (int m = 0; m < 4; ++m)
#pragma unroll
      for (int r = 0; r < 4; ++r) {
        float x = fmaxf(fmaxf(acc[m][0][r], acc[m][1][r]),
                        fmaxf(acc[m][2][r], acc[m][3][r]));
        x = fmaxf(x, __shfl_xor(x, 1));
        x = fmaxf(x, __shfl_xor(x, 2));
        x = fmaxf(x, __shfl_xor(x, 4));
        x = fmaxf(x, __shfl_xor(x, 8));
        rmax[m][r] = fmaxf(x, 1e-30f);
      }
    if (c4 == 0) {
#pragma unroll
      for (int m = 0; m < 4; ++m)
#pragma unroll
        for (int r = 0; r < 4; ++r)
          pmAcc[16 * m + 4 * q + r] += nu + __logf(rmax[m][r]);
    }
  };

  auto roundtrip = [&](unsigned short* ps) {
#pragma unroll
    for (int m = 0; m < 4; ++m) {
      float i0 = __builtin_amdgcn_rcpf(rmax[m][0]);
      float i1 = __builtin_amdgcn_rcpf(rmax[m][1]);
      float i2 = __builtin_amdgcn_rcpf(rmax[m][2]);
      float i3 = __builtin_amdgcn_rcpf(rmax[m][3]);
#pragma unroll
      for (int n = 0; n < 4; ++n) {
        unsigned p01 = cvtpk(acc[m][n][0] * i0, acc[m][n][1] * i1);
        unsigned p23 = cvtpk(acc[m][n][2] * i2, acc[m][n][3] * i3);
        ps[(16 * m + 4 * q + 0) * PMS + 16 * n + c4] = (unsigned short)(p01 & 0xffffu);
        ps[(16 * m + 4 * q + 1) * PMS + 16 * n + c4] = (unsigned short)(p01 >> 16);
        ps[(16 * m + 4 * q + 2) * PMS + 16 * n + c4] = (unsigned short)(p23 & 0xffffu);
        ps[(16 * m + 4 * q + 3) * PMS + 16 * n + c4] = (unsigned short)(p23 >> 16);
      }
    }
#pragma unroll
    for (int m = 0; m < 4; ++m)
#pragma unroll
      for (int h = 0; h < 2; ++h)
        afr[m][h] = *(const s16x8*)&ps[(16 * m + c4) * PMS + 32 * h + 8 * q];
  };

  auto storeEt = [&](unsigned short* pd) {
#pragma unroll
    for (int m = 0; m < 4; ++m) {
      float i0 = __builtin_amdgcn_rcpf(rmax[m][0]);
      float i1 = __builtin_amdgcn_rcpf(rmax[m][1]);
      float i2 = __builtin_amdgcn_rcpf(rmax[m][2]);
      float i3 = __builtin_amdgcn_rcpf(rmax[m][3]);
#pragma unroll
      for (int n = 0; n < 4; ++n) {
        unsigned p01 = cvtpk(acc[m][n][0] * i0, acc[m][n][1] * i1);
        unsigned p23 = cvtpk(acc[m][n][2] * i2, acc[m][n][3] * i3);
        u64t packed = (u64t)p01 | ((u64t)p23 << 32);
        *(u64t*)&pd[(16 * n + c4) * PMS + 16 * m + 4 * q] = packed;
      }
    }
  };

  // ---- level 0: wave v folds transposed chunks s=16v..16v+15
  //      (global chunk index 127-16v down to 112-16v)
  {
    const int cidx0 = b * HMM_C + 127 - 16 * v;
    u32x4 braw[2][4];
    float mv;
#pragma unroll
    for (int h = 0; h < 2; ++h)
#pragma unroll
      for (int n = 0; n < 4; ++n)
        braw[h][n] = *(const u32x4*)&Xt[(size_t)cidx0 * 4096 +
                                        (16 * n + c4) * 64 + 32 * h + 8 * q];
    mv = M[(size_t)cidx0 * 64 + l];

    for (int c = 0; c < 16; ++c) {
      u32x4 bcur[2][4];
#pragma unroll
      for (int h = 0; h < 2; ++h)
#pragma unroll
        for (int n = 0; n < 4; ++n) bcur[h][n] = braw[h][n];
      float mcur = mv;
      if (c < 15) {
        const size_t cb = (size_t)(cidx0 - (c + 1)) * 4096;
#pragma unroll
        for (int h = 0; h < 2; ++h)
#pragma unroll
          for (int n = 0; n < 4; ++n)
            braw[h][n] = *(const u32x4*)&Xt[cb + (16 * n + c4) * 64 + 32 * h + 8 * q];
        mv = M[(size_t)(cidx0 - (c + 1)) * 64 + l];
      }
      fold(bcur, mcur, pm[v], sS[v]);
      if (c < 15) roundtrip(pmat[v]);
      else        storeEt(pmat[v]);
    }
  }
  __syncthreads();

  // ---- level 1: waves 0,1 fold partial slots [4v, 4v+4)
  if (v < 2) {
    const int sb = 4 * v;
#pragma unroll
    for (int m = 0; m < 4; ++m)
#pragma unroll
      for (int h = 0; h < 2; ++h)
#pragma unroll
        for (int e = 0; e < 8; ++e)
          afr[m][h][e] = (short)pmat[sb][(32 * h + 8 * q + e) * PMS + 16 * m + c4];
    for (int c = 1; c < 4; ++c) {
      u32x4 bcur[2][4];
#pragma unroll
      for (int h = 0; h < 2; ++h)
#pragma unroll
        for (int n = 0; n < 4; ++n)
          bcur[h][n] = *(const u32x4*)&pmat[sb + c][(16 * n + c4) * PMS + 32 * h + 8 * q];
      float mcur = pm[sb + c][l];
      fold(bcur, mcur, pm[sb], sS[v]);
      if (v == 0)      roundtrip(pmat[0]);
      else if (c < 3)  roundtrip(pmat[4]);
      else             storeEt(pmat[4]);
    }
  }
  __syncthreads();

  // ---- level 2 + final
  if (v == 0) {
    u32x4 bcur[2][4];
#pragma unroll
    for (int h = 0; h < 2; ++h)
#pragma unroll
      for (int n = 0; n < 4; ++n)
        bcur[h][n] = *(const u32x4*)&pmat[4][(16 * n + c4) * PMS + 32 * h + 8 * q];
    float mcur = pm[4][l];

    float nu = mcur;
    nu = fmaxf(nu, __shfl_xor(nu, 1));  nu = fmaxf(nu, __shfl_xor(nu, 2));
    nu = fmaxf(nu, __shfl_xor(nu, 4));  nu = fmaxf(nu, __shfl_xor(nu, 8));
    nu = fmaxf(nu, __shfl_xor(nu, 16)); nu = fmaxf(nu, __shfl_xor(nu, 32));
    sS[0][l] = __expf(mcur - nu);
    s16x8 bfr[2][4];
#pragma unroll
    for (int h = 0; h < 2; ++h) {
      f32x4 s0 = *(const f32x4*)&sS[0][h * 32 + q * 8];
      f32x4 s1 = *(const f32x4*)&sS[0][h * 32 + q * 8 + 4];
#pragma unroll
      for (int n = 0; n < 4; ++n) {
        u32x4 raw = bcur[h][n];
        unsigned p0 = cvtpk(bflo(raw.x) * s0[0], bfhi(raw.x) * s0[1]);
        unsigned p1 = cvtpk(bflo(raw.y) * s0[2], bfhi(raw.y) * s0[3]);
        unsigned p2 = cvtpk(bflo(raw.z) * s1[0], bfhi(raw.z) * s1[1]);
        unsigned p3 = cvtpk(bflo(raw.w) * s1[2], bfhi(raw.w) * s1[3]);
        u32x4 o; o.x = p0; o.y = p1; o.z = p2; o.w = p3;
        bfr[h][n] = *(s16x8*)&o;
      }
    }
#pragma unroll
    for (int m = 0; m < 4; ++m)
#pragma unroll
      for (int n = 0; n < 4; ++n) {
        f32x4 c = {0.f, 0.f, 0.f, 0.f};
        c = __builtin_amdgcn_mfma_f32_16x16x32_bf16(afr[m][0], bfr[0][n], c, 0, 0, 0);
        c = __builtin_amdgcn_mfma_f32_16x16x32_bf16(afr[m][1], bfr[1][n], c, 0, 0, 0);
        acc[m][n] = c;
      }

    // acc = Mt (unnorm.); true M^T = diag(e^pm0) . acc . e^nu
    // out = nu + mL + kap + log( sum_j e^{pm0_j-kap} * sum_i acc[j][i] e^{linit_i-mL} )
    float tl = sLin[l];
    float mL = tl;
    mL = fmaxf(mL, __shfl_xor(mL, 1));  mL = fmaxf(mL, __shfl_xor(mL, 2));
    mL = fmaxf(mL, __shfl_xor(mL, 4));  mL = fmaxf(mL, __shfl_xor(mL, 8));
    mL = fmaxf(mL, __shfl_xor(mL, 16)); mL = fmaxf(mL, __shfl_xor(mL, 32));
    float wn[4];
#pragma unroll
    for (int n = 0; n < 4; ++n) wn[n] = __expf(sLin[16 * n + c4] - mL);

    float pj = pm[0][l];
    float kap = pj;
    kap = fmaxf(kap, __shfl_xor(kap, 1));  kap = fmaxf(kap, __shfl_xor(kap, 2));
    kap = fmaxf(kap, __shfl_xor(kap, 4));  kap = fmaxf(kap, __shfl_xor(kap, 8));
    kap = fmaxf(kap, __shfl_xor(kap, 16)); kap = fmaxf(kap, __shfl_xor(kap, 32));

    float tot = 0.f;
#pragma unroll
    for (int m = 0; m < 4; ++m)
#pragma unroll
      for (int r = 0; r < 4; ++r) {
        float p = acc[m][0][r] * wn[0] + acc[m][1][r] * wn[1] +
                  acc[m][2][r] * wn[2] + acc[m][3][r] * wn[3];
        p += __shfl_xor(p, 1); p += __shfl_xor(p, 2);
        p += __shfl_xor(p, 4); p += __shfl_xor(p, 8);
        if (c4 == 0) {
          int j = 16 * m + 4 * q + r;
          tot += __expf(pm[0][j] - kap) * p;
        }
      }
    tot += __shfl_xor(tot, 16);
    tot += __shfl_xor(tot, 32);
    if (l == 0) out[b] = nu + mL + kap + __logf(tot);
  }
}

extern "C" void kernel_launch(void* const* d_in, const int* in_sizes, int n_in,
                              void* d_out, int out_size, void* d_ws, size_t ws_size,
                              hipStream_t stream) {
  (void)in_sizes; (void)n_in; (void)out_size; (void)ws_size;
  const float* lf    = (const float*)d_in[0];  // [B,T,S,S] fp32
  const float* linit = (const float*)d_in[1];  // [B,S] fp32
  float* out = (float*)d_out;                  // [B] fp32

  unsigned short* wsX = (unsigned short*)d_ws;                  // 8 MB bf16
  float*          wsM = (float*)(wsX + (size_t)1024 * 4096);    // 256 KB f32

  hmm_phase1<<<dim3(HMM_B * HMM_C), dim3(256), 0, stream>>>(lf, wsX, wsM);
  hmm_reduce<<<dim3(HMM_B), dim3(512), 0, stream>>>(wsX, wsM, linit, out);
}